// Round 16
// baseline (184.650 us; speedup 1.0000x reference)
//
#include <hip/hip_runtime.h>
#include <hip/hip_bf16.h>

#define HH 448
#define WW 160
#define NPIX (HH*WW)
#define BCOL 80

typedef unsigned long long u64;
typedef _Float16 h8 __attribute__((ext_vector_type(8)));
typedef _Float16 h4 __attribute__((ext_vector_type(4)));
typedef float f32x4 __attribute__((ext_vector_type(4)));

#define MFMA16(A,B,C) __builtin_amdgcn_mfma_f32_16x16x32_f16(A,B,C,0,0,0)
#define LO_SCALE 4096.0f
#define LO_INV   (1.0f/4096.0f)

__device__ __forceinline__ float leaky(float v) { return v >= 0.f ? v : 0.01f * v; }

__device__ __forceinline__ u64 packKey(float m, int r) {
    unsigned u = __float_as_uint(m);
    u = (u & 0x80000000u) ? ~u : (u | 0x80000000u);   // monotone f32 -> u32
    return ((u64)u << 32) | (unsigned)(255 - r);       // ties -> lowest idx
}

// split a fp32 into fp16 hi + scaled fp16 lo:  a ~= hi + lo*2^-12  (|err| <= 2^-24 |a|)
__device__ __forceinline__ _Float16 splitHi(float v) { return (_Float16)v; }
__device__ __forceinline__ _Float16 splitLo(float v, _Float16 hi) {
    return (_Float16)((v - (float)hi) * LO_SCALE);
}

__device__ __forceinline__ void cvtA(const float4& v0, const float4& v1, h8& ah, h8& al) {
    const float v[8] = {v0.x,v0.y,v0.z,v0.w,v1.x,v1.y,v1.z,v1.w};
#pragma unroll
    for (int j = 0; j < 8; ++j) {
        const _Float16 hi = splitHi(v[j]);
        ah[j] = hi;
        al[j] = splitLo(v[j], hi);
    }
}

// One pass: 1 row-tile x 5 col-tiles of 16x16 out, K=128 (4 MFMA K-steps), 3-term split.
// Software-pipelined CONVERSION: cvt(s+1) issues before mfma(s) (independent ->
// VALU fills the matrix pipe's shadow); cvt(s+2) issues after the mfma blocks,
// once its load (issued at iter start) has landed. Load rotation = round-14 (no spill).
// Same ops on same data, only instruction order changes -> bitwise-identical outputs.
__device__ __forceinline__ void gemmPass(const _Float16* lah, const _Float16* lal,
                                         const float* __restrict__ Wp,
                                         int lrow, int lg,
                                         f32x4 aH[5], f32x4 aL[5])
{
    const f32x4 zero = {0.f, 0.f, 0.f, 0.f};
#pragma unroll
    for (int c = 0; c < 5; ++c) { aH[c] = zero; aL[c] = zero; }

    const float* wb = Wp + lrow * 128 + lg * 8;
    float4 ca0 = *(const float4*)(wb);
    float4 ca1 = *(const float4*)(wb + 4);
    float4 cb0 = *(const float4*)(wb + 32);
    float4 cb1 = *(const float4*)(wb + 36);

    h8 AhA, AlA;
    cvtA(ca0, ca1, AhA, AlA);            // A(s=0) ready before the loop

    const int ub = lrow;                 // B base col within the 80-col block

#pragma unroll 1
    for (int s = 0; s < 4; s += 2) {
        const int sa = (s + 2) & 3, sb = (s + 3) & 3;   // wrap: s=2 re-reads 0/1 (cache-hot)
        float4 na0 = *(const float4*)(wb + sa * 32);
        float4 na1 = *(const float4*)(wb + sa * 32 + 4);
        float4 nb0 = *(const float4*)(wb + sb * 32);
        float4 nb1 = *(const float4*)(wb + sb * 32 + 4);

        h8 AhB, AlB;
        cvtA(cb0, cb1, AhB, AlB);        // cvt(s+1): independent of mfma(s) below
        {
            const int gg = (s << 2) + lg;
#pragma unroll
            for (int c = 0; c < 5; ++c) {
                const int u = gg * BCOL + ub + (c << 4);
                const h8 Bh = *(const h8*)(lah + (u << 3));
                const h8 Bl = *(const h8*)(lal + (u << 3));
                aH[c] = MFMA16(AhA, Bh, aH[c]);
                aL[c] = MFMA16(AhA, Bl, aL[c]);
                aL[c] = MFMA16(AlA, Bh, aL[c]);
            }
        }
        {
            const int gg = ((s + 1) << 2) + lg;
#pragma unroll
            for (int c = 0; c < 5; ++c) {
                const int u = gg * BCOL + ub + (c << 4);
                const h8 Bh = *(const h8*)(lah + (u << 3));
                const h8 Bl = *(const h8*)(lal + (u << 3));
                aH[c] = MFMA16(AhB, Bh, aH[c]);
                aL[c] = MFMA16(AhB, Bl, aL[c]);
                aL[c] = MFMA16(AlB, Bh, aL[c]);
            }
        }
        if (s == 0) cvtA(na0, na1, AhA, AlA);   // cvt(s=2): its load has landed during the mfmas
        cb0 = nb0; cb1 = nb1;
    }
}

__global__ __launch_bounds__(512, 4) void kA(
    const float* __restrict__ x_in,
    const float* __restrict__ Wcl1, const float* __restrict__ bcl1,
    const float* __restrict__ Wcl2, const float* __restrict__ bcl2,
    const float* __restrict__ Wcl3, const float* __restrict__ bcl3,
    const float* __restrict__ Wcl4, const float* __restrict__ bcl4,
    const float* __restrict__ Wreg1, const float* __restrict__ breg1,
    __hip_bfloat16* __restrict__ xr, int* __restrict__ ind, float* __restrict__ out)
{
    // 8-wave block, 80 cols of one h. LDS exactly 40960 B -> 2 blocks/CU (16 waves).
    __shared__ alignas(16) _Float16 lah[16 * BCOL * 8];   // 20480 B: act hi, K-packed
    __shared__ alignas(16) _Float16 lal[16 * BCOL * 8];   // 20480 B: act lo*4096
    u64* argb = reinterpret_cast<u64*>(lah);  // aliased AFTER act is dead (post-cl4)

    // XCD pairing: both 80-col halves of one h land on the same XCD (bid%8)
    const int bid = blockIdx.x;
    const int r16 = bid & 15;
    const int h = ((bid >> 4) << 3) | (r16 & 7);
    const int w0 = ((r16 >> 3) & 1) * BCOL;

    const int t = threadIdx.x;
    const int wvid = t >> 6;                 // 0..7
    const int l = t & 63;
    const int lrow = l & 15, lg = l >> 4;
    const int trb = wvid * 16;               // wave's row base within a 128-row pass

    // ---- stage x: fp32 -> fp16-split pairs, K-packed [g][col][8] ----
#pragma unroll 1
    for (int k = 0; k < 3; ++k) {
        const int id = t + (k << 9);         // 0..1279 = (g, col)
        if (id < 16 * BCOL) {
            const int g = id / BCOL, col = id - g * BCOL;
            float v[8];
#pragma unroll
            for (int j = 0; j < 8; ++j)
                v[j] = x_in[(size_t)(g * 8 + j) * 71680 + h * 160 + w0 + col];
            h8 hh, ll;
#pragma unroll
            for (int j = 0; j < 8; ++j) {
                const _Float16 hi = splitHi(v[j]);
                hh[j] = hi;
                ll[j] = splitLo(v[j], hi);
            }
            const int u = g * BCOL + col;
            *(h8*)(lah + (u << 3)) = hh;
            *(h8*)(lal + (u << 3)) = ll;
        }
    }
    __syncthreads();

    // ---- reg1: 256 rows in 2 passes, bf16 out to xr (no LDS writes) ----
    {
        const float* W1 = Wreg1 + (size_t)h * 32768;
        const float* b1 = breg1 + h * 256;
#pragma unroll 1
        for (int p = 0; p < 2; ++p) {
            const int rowOff = (p << 7) + trb;
            f32x4 aH[5], aL[5];
            gemmPass(lah, lal, W1 + rowOff * 128, lrow, lg, aH, aL);
            const int r0 = rowOff + (lg << 2);
            const float4 bb = *(const float4*)&b1[r0];
#pragma unroll
            for (int c = 0; c < 5; ++c) {
                const int col = w0 + (c << 4) + lrow;
                alignas(8) unsigned short us[4];
#pragma unroll
                for (int r = 0; r < 4; ++r) {
                    const float a = aH[c][r] + aL[c][r] * LO_INV + ((const float*)&bb)[r];
                    __hip_bfloat16 bv = __float2bfloat16(leaky(a));
                    us[r] = *(const unsigned short*)&bv;
                }
                *(uint2*)(xr + (((size_t)(h * 160 + col)) << 8) + r0) = *(const uint2*)us;
            }
        }
    }

    // ---- cl1..cl3: in-place act update (compute -> barrier -> write -> barrier) ----
#pragma unroll 1
    for (int L = 0; L < 3; ++L) {
        const float* W = (L == 0) ? Wcl1 + (size_t)h * 16384
                       : (L == 1) ? Wcl2 + (size_t)h * 16384
                                  : Wcl3 + (size_t)h * 16384;
        const float* b = (L == 0) ? bcl1 + (h << 7)
                       : (L == 1) ? bcl2 + (h << 7)
                                  : bcl3 + (h << 7);
        f32x4 aH[5], aL[5];
        gemmPass(lah, lal, W + trb * 128, lrow, lg, aH, aL);
        const int r0 = trb + (lg << 2);
        const float4 bb = *(const float4*)&b[r0];
        float nv[5][4];
#pragma unroll
        for (int c = 0; c < 5; ++c)
#pragma unroll
            for (int rr = 0; rr < 4; ++rr)
                nv[c][rr] = leaky(aH[c][rr] + aL[c][rr] * LO_INV + ((const float*)&bb)[rr]);
        __syncthreads();                 // all reads of old act done
        {
            const int g = r0 >> 3, off = r0 & 7;
#pragma unroll
            for (int c = 0; c < 5; ++c) {
                const int col = (c << 4) + lrow;
                h4 wh, wl;
#pragma unroll
                for (int rr = 0; rr < 4; ++rr) {
                    const _Float16 hi = splitHi(nv[c][rr]);
                    wh[rr] = hi;
                    wl[rr] = splitLo(nv[c][rr], hi);
                }
                *(h4*)(lah + ((g * BCOL + col) << 3) + off) = wh;
                *(h4*)(lal + ((g * BCOL + col) << 3) + off) = wl;
            }
        }
        __syncthreads();
    }

    // ---- mask row (pre-cl4; act holds cl3 output — identical values) ----
    if (t < BCOL) {
        const float* Wm = Wcl4 + (size_t)h * 32896 + 32768;   // class row 256
        float accm = 0.f;
#pragma unroll 2
        for (int g = 0; g < 16; ++g) {
            const h8 hv = *(const h8*)(lah + ((g * BCOL + t) << 3));
            const h8 lv = *(const h8*)(lal + ((g * BCOL + t) << 3));
            const float4 wv0 = *(const float4*)&Wm[g * 8];
            const float4 wv1 = *(const float4*)&Wm[g * 8 + 4];
            const float wv[8] = {wv0.x,wv0.y,wv0.z,wv0.w,wv1.x,wv1.y,wv1.z,wv1.w};
#pragma unroll
            for (int j = 0; j < 8; ++j)
                accm = fmaf(wv[j], (float)hv[j] + (float)lv[j] * LO_INV, accm);
        }
        out[NPIX + h * 160 + w0 + t] = leaky(accm + bcl4[h * 257 + 256]);
    }

    // ---- cl4: 256 class rows in 2 passes; argmax in registers ----
    float mv[5]; int mr[5];
    {
        const float* W4 = Wcl4 + (size_t)h * 32896;
        const float* b4 = bcl4 + h * 257;
#pragma unroll
        for (int c = 0; c < 5; ++c) { mv[c] = -3.4e38f; mr[c] = 0; }
#pragma unroll 1
        for (int p = 0; p < 2; ++p) {
            const int rowOff = (p << 7) + trb;
            f32x4 aH[5], aL[5];
            gemmPass(lah, lal, W4 + rowOff * 128, lrow, lg, aH, aL);
            const int r0 = rowOff + (lg << 2);
            const float4 bb = *(const float4*)&b4[r0];
#pragma unroll
            for (int c = 0; c < 5; ++c)
#pragma unroll
                for (int rr = 0; rr < 4; ++rr) {
                    const float a = aH[c][rr] + aL[c][rr] * LO_INV + ((const float*)&bb)[rr];
                    if (a > mv[c]) { mv[c] = a; mr[c] = r0 + rr; }   // rows ascending per lane
                }
        }
    }
    __syncthreads();                     // act (incl. mask) reads complete; lah now dead
    if (t < BCOL) argb[t] = 0ull;        // argb aliases lah
    __syncthreads();
#pragma unroll
    for (int c = 0; c < 5; ++c)
        atomicMax(&argb[(c << 4) + lrow], packKey(mv[c], mr[c]));
    __syncthreads();

    // ---- finalize: ind ----
    if (t < BCOL) {
        const u64 kk = argb[t];
        ind[h * 160 + w0 + t] = 255 - (int)(kk & 0xFFu);
    }
}

__global__ __launch_bounds__(256) void kB(
    const __hip_bfloat16* __restrict__ xr, const int* __restrict__ ind,
    const float* __restrict__ Wcm2, const float* __restrict__ bcm2,
    const float* __restrict__ Wcm3, const float* __restrict__ bcm3,
    float* __restrict__ out)
{
    // Contiguous mapping: wave wid handles n in [wid*10, wid*10+10).
    // unroll 2: next-n gather loads issue under current-n compute (L2 latency hiding).
    const int wid = (int)((blockIdx.x * blockDim.x + threadIdx.x) >> 6);
    const int lane = threadIdx.x & 63;

#pragma unroll 2
    for (int k = 0; k < 10; ++k) {
        const int n = wid * 10 + k;
        const int h_o = n % HH, w_o = n / HH;   // xr source & output position (w-major flat)
        const int h_i = n / WW, w_i = n % WW;   // index-gather position (h-major flat)
        const int ig = ind[h_i * WW + w_i];
        const int sc = (ig >> 4) + (h_i << 4);
        const int rr = ig + (h_i << 8);

        const __hip_bfloat16* xp = xr + (size_t)(h_o * WW + w_o) * 256;
        const float* Wp = Wcm2 + (size_t)sc * 2048;

        float acc[8];
#pragma unroll
        for (int o = 0; o < 8; ++o) acc[o] = 0.f;

        const int c0 = lane * 4;
        const ushort4 xv4 = *(const ushort4*)((const unsigned short*)xp + c0);
        float xf[4];
        xf[0] = __uint_as_float((unsigned int)xv4.x << 16);
        xf[1] = __uint_as_float((unsigned int)xv4.y << 16);
        xf[2] = __uint_as_float((unsigned int)xv4.z << 16);
        xf[3] = __uint_as_float((unsigned int)xv4.w << 16);

#pragma unroll
        for (int i = 0; i < 4; ++i) {
            const float4* wrow = (const float4*)&Wp[(c0 + i) * 8];
            const float4 wa = wrow[0];
            const float4 wb_ = wrow[1];
            const float x = xf[i];
            acc[0] += x * wa.x;  acc[1] += x * wa.y;  acc[2] += x * wa.z;  acc[3] += x * wa.w;
            acc[4] += x * wb_.x; acc[5] += x * wb_.y; acc[6] += x * wb_.z; acc[7] += x * wb_.w;
        }
#pragma unroll
        for (int o = 0; o < 8; ++o) {
            float v = acc[o];
#pragma unroll
            for (int d = 32; d > 0; d >>= 1) v += __shfl_xor(v, d, 64);
            acc[o] = v;
        }
        float r = bcm3[rr];
        const float* b2 = bcm2 + (size_t)sc * 8;
        const float* w3 = Wcm3 + (size_t)rr * 8;
#pragma unroll
        for (int o = 0; o < 8; ++o) {
            const float y = leaky(acc[o] + b2[o]);
            r += y * w3[o];
        }
        if (lane == 0) {
            const float iv = (float)ind[h_o * WW + w_o];
            out[h_o * WW + w_o] = (iv + r) * (1.0f / 256.0f);
        }
    }
}

extern "C" void kernel_launch(void* const* d_in, const int* in_sizes, int n_in,
                              void* d_out, int out_size, void* d_ws, size_t ws_size,
                              hipStream_t stream)
{
    const float* x_in  = (const float*)d_in[0];
    const float* Wcl1  = (const float*)d_in[1];
    const float* bcl1  = (const float*)d_in[2];
    const float* Wcl2  = (const float*)d_in[3];
    const float* bcl2  = (const float*)d_in[4];
    const float* Wcl3  = (const float*)d_in[5];
    const float* bcl3  = (const float*)d_in[6];
    const float* Wcl4  = (const float*)d_in[7];
    const float* bcl4  = (const float*)d_in[8];
    const float* Wreg1 = (const float*)d_in[9];
    const float* breg1 = (const float*)d_in[10];
    const float* Wcm2  = (const float*)d_in[11];
    const float* bcm2  = (const float*)d_in[12];
    const float* Wcm3  = (const float*)d_in[13];
    const float* bcm3  = (const float*)d_in[14];

    float* out = (float*)d_out;

    // workspace: x_r as bf16 [448][160][256], then ind int32 [448*160]
    __hip_bfloat16* xr = (__hip_bfloat16*)d_ws;
    int* ind = (int*)((char*)d_ws + (size_t)NPIX * 256 * sizeof(__hip_bfloat16));

    kA<<<dim3(HH * 2), dim3(512), 0, stream>>>(x_in, Wcl1, bcl1, Wcl2, bcl2, Wcl3, bcl3,
                                               Wcl4, bcl4, Wreg1, breg1, xr, ind, out);
    kB<<<dim3(1792), dim3(256), 0, stream>>>(xr, ind, Wcm2, bcm2, Wcm3, bcm3, out);
}

// Round 17
// 172.928 us; speedup vs baseline: 1.0678x; 1.0678x over previous
//
#include <hip/hip_runtime.h>
#include <hip/hip_bf16.h>

#define HH 448
#define WW 160
#define NPIX (HH*WW)
#define BCOL 80

typedef unsigned long long u64;
typedef _Float16 h8 __attribute__((ext_vector_type(8)));
typedef _Float16 h4 __attribute__((ext_vector_type(4)));
typedef float f32x4 __attribute__((ext_vector_type(4)));

#define MFMA16(A,B,C) __builtin_amdgcn_mfma_f32_16x16x32_f16(A,B,C,0,0,0)
#define LO_SCALE 4096.0f
#define LO_INV   (1.0f/4096.0f)

__device__ __forceinline__ float leaky(float v) { return v >= 0.f ? v : 0.01f * v; }

__device__ __forceinline__ u64 packKey(float m, int r) {
    unsigned u = __float_as_uint(m);
    u = (u & 0x80000000u) ? ~u : (u | 0x80000000u);   // monotone f32 -> u32
    return ((u64)u << 32) | (unsigned)(255 - r);       // ties -> lowest idx
}

// split a fp32 into fp16 hi + scaled fp16 lo:  a ~= hi + lo*2^-12  (|err| <= 2^-24 |a|)
__device__ __forceinline__ _Float16 splitHi(float v) { return (_Float16)v; }
__device__ __forceinline__ _Float16 splitLo(float v, _Float16 hi) {
    return (_Float16)((v - (float)hi) * LO_SCALE);
}

__device__ __forceinline__ void cvtA(const float4& v0, const float4& v1, h8& ah, h8& al) {
    const float v[8] = {v0.x,v0.y,v0.z,v0.w,v1.x,v1.y,v1.z,v1.w};
#pragma unroll
    for (int j = 0; j < 8; ++j) {
        const _Float16 hi = splitHi(v[j]);
        ah[j] = hi;
        al[j] = splitLo(v[j], hi);
    }
}

// One pass: 1 row-tile x 5 col-tiles of 16x16 out, K=128 (4 MFMA K-steps), 3-term split.
// Rolled s-loop with 2-K-step rotating weight prefetch (round-14/15 verified, no spill).
// Accumulation order identical to the verified round-8..15 kernels (bitwise-same).
__device__ __forceinline__ void gemmPass(const _Float16* lah, const _Float16* lal,
                                         const float* __restrict__ Wp,
                                         int lrow, int lg,
                                         f32x4 aH[5], f32x4 aL[5])
{
    const f32x4 zero = {0.f, 0.f, 0.f, 0.f};
#pragma unroll
    for (int c = 0; c < 5; ++c) { aH[c] = zero; aL[c] = zero; }

    const float* wb = Wp + lrow * 128 + lg * 8;
    float4 ca0 = *(const float4*)(wb);
    float4 ca1 = *(const float4*)(wb + 4);
    float4 cb0 = *(const float4*)(wb + 32);
    float4 cb1 = *(const float4*)(wb + 36);

    const int ub = lrow;                     // B base col within the 80-col block

#pragma unroll 1
    for (int s = 0; s < 4; s += 2) {
        const int sa = (s + 2) & 3, sb = (s + 3) & 3;   // wrap: s=2 re-reads 0/1 (cache-hot)
        float4 na0 = *(const float4*)(wb + sa * 32);
        float4 na1 = *(const float4*)(wb + sa * 32 + 4);
        float4 nb0 = *(const float4*)(wb + sb * 32);
        float4 nb1 = *(const float4*)(wb + sb * 32 + 4);

        h8 Ah, Al;
        cvtA(ca0, ca1, Ah, Al);
        {
            const int gg = (s << 2) + lg;
#pragma unroll
            for (int c = 0; c < 5; ++c) {
                const int u = gg * BCOL + ub + (c << 4);
                const h8 Bh = *(const h8*)(lah + (u << 3));
                const h8 Bl = *(const h8*)(lal + (u << 3));
                aH[c] = MFMA16(Ah, Bh, aH[c]);
                aL[c] = MFMA16(Ah, Bl, aL[c]);
                aL[c] = MFMA16(Al, Bh, aL[c]);
            }
        }
        cvtA(cb0, cb1, Ah, Al);
        {
            const int gg = ((s + 1) << 2) + lg;
#pragma unroll
            for (int c = 0; c < 5; ++c) {
                const int u = gg * BCOL + ub + (c << 4);
                const h8 Bh = *(const h8*)(lah + (u << 3));
                const h8 Bl = *(const h8*)(lal + (u << 3));
                aH[c] = MFMA16(Ah, Bh, aH[c]);
                aL[c] = MFMA16(Ah, Bl, aL[c]);
                aL[c] = MFMA16(Al, Bh, aL[c]);
            }
        }
        ca0 = na0; ca1 = na1; cb0 = nb0; cb1 = nb1;
    }
}

__global__ __launch_bounds__(512, 4) void kA(
    const float* __restrict__ x_in,
    const float* __restrict__ Wcl1, const float* __restrict__ bcl1,
    const float* __restrict__ Wcl2, const float* __restrict__ bcl2,
    const float* __restrict__ Wcl3, const float* __restrict__ bcl3,
    const float* __restrict__ Wcl4, const float* __restrict__ bcl4,
    const float* __restrict__ Wreg1, const float* __restrict__ breg1,
    __hip_bfloat16* __restrict__ xr, int* __restrict__ ind, float* __restrict__ out)
{
    // 8-wave block, 80 cols of one h. LDS exactly 40960 B -> 2 blocks/CU (16 waves).
    __shared__ alignas(16) _Float16 lah[16 * BCOL * 8];   // 20480 B: act hi, K-packed
    __shared__ alignas(16) _Float16 lal[16 * BCOL * 8];   // 20480 B: act lo*4096
    u64* argb = reinterpret_cast<u64*>(lah);  // aliased AFTER act is dead (post-cl4)

    // XCD pairing: both 80-col halves of one h land on the same XCD (bid%8)
    const int bid = blockIdx.x;
    const int r16 = bid & 15;
    const int h = ((bid >> 4) << 3) | (r16 & 7);
    const int w0 = ((r16 >> 3) & 1) * BCOL;

    const int t = threadIdx.x;
    const int wvid = t >> 6;                 // 0..7
    const int l = t & 63;
    const int lrow = l & 15, lg = l >> 4;
    const int trb = wvid * 16;               // wave's row base within a 128-row pass

    // ---- stage x: fp32 -> fp16-split pairs, K-packed [g][col][8] ----
#pragma unroll 1
    for (int k = 0; k < 3; ++k) {
        const int id = t + (k << 9);         // 0..1279 = (g, col)
        if (id < 16 * BCOL) {
            const int g = id / BCOL, col = id - g * BCOL;
            float v[8];
#pragma unroll
            for (int j = 0; j < 8; ++j)
                v[j] = x_in[(size_t)(g * 8 + j) * 71680 + h * 160 + w0 + col];
            h8 hh, ll;
#pragma unroll
            for (int j = 0; j < 8; ++j) {
                const _Float16 hi = splitHi(v[j]);
                hh[j] = hi;
                ll[j] = splitLo(v[j], hi);
            }
            const int u = g * BCOL + col;
            *(h8*)(lah + (u << 3)) = hh;
            *(h8*)(lal + (u << 3)) = ll;
        }
    }
    __syncthreads();

    // ---- reg1: 256 rows in 2 passes, bf16 out to xr (no LDS writes) ----
    {
        const float* W1 = Wreg1 + (size_t)h * 32768;
        const float* b1 = breg1 + h * 256;
#pragma unroll 1
        for (int p = 0; p < 2; ++p) {
            const int rowOff = (p << 7) + trb;
            f32x4 aH[5], aL[5];
            gemmPass(lah, lal, W1 + rowOff * 128, lrow, lg, aH, aL);
            const int r0 = rowOff + (lg << 2);
            const float4 bb = *(const float4*)&b1[r0];
#pragma unroll
            for (int c = 0; c < 5; ++c) {
                const int col = w0 + (c << 4) + lrow;
                alignas(8) unsigned short us[4];
#pragma unroll
                for (int r = 0; r < 4; ++r) {
                    const float a = aH[c][r] + aL[c][r] * LO_INV + ((const float*)&bb)[r];
                    __hip_bfloat16 bv = __float2bfloat16(leaky(a));
                    us[r] = *(const unsigned short*)&bv;
                }
                *(uint2*)(xr + (((size_t)(h * 160 + col)) << 8) + r0) = *(const uint2*)us;
            }
        }
    }

    // ---- cl1..cl3: in-place act update (compute -> barrier -> write -> barrier) ----
#pragma unroll 1
    for (int L = 0; L < 3; ++L) {
        const float* W = (L == 0) ? Wcl1 + (size_t)h * 16384
                       : (L == 1) ? Wcl2 + (size_t)h * 16384
                                  : Wcl3 + (size_t)h * 16384;
        const float* b = (L == 0) ? bcl1 + (h << 7)
                       : (L == 1) ? bcl2 + (h << 7)
                                  : bcl3 + (h << 7);
        f32x4 aH[5], aL[5];
        gemmPass(lah, lal, W + trb * 128, lrow, lg, aH, aL);
        const int r0 = trb + (lg << 2);
        const float4 bb = *(const float4*)&b[r0];
        float nv[5][4];
#pragma unroll
        for (int c = 0; c < 5; ++c)
#pragma unroll
            for (int rr = 0; rr < 4; ++rr)
                nv[c][rr] = leaky(aH[c][rr] + aL[c][rr] * LO_INV + ((const float*)&bb)[rr]);
        __syncthreads();                 // all reads of old act done
        {
            const int g = r0 >> 3, off = r0 & 7;
#pragma unroll
            for (int c = 0; c < 5; ++c) {
                const int col = (c << 4) + lrow;
                h4 wh, wl;
#pragma unroll
                for (int rr = 0; rr < 4; ++rr) {
                    const _Float16 hi = splitHi(nv[c][rr]);
                    wh[rr] = hi;
                    wl[rr] = splitLo(nv[c][rr], hi);
                }
                *(h4*)(lah + ((g * BCOL + col) << 3) + off) = wh;
                *(h4*)(lal + ((g * BCOL + col) << 3) + off) = wl;
            }
        }
        __syncthreads();
    }

    // ---- mask row (pre-cl4; act holds cl3 output — identical values) ----
    if (t < BCOL) {
        const float* Wm = Wcl4 + (size_t)h * 32896 + 32768;   // class row 256
        float accm = 0.f;
#pragma unroll 2
        for (int g = 0; g < 16; ++g) {
            const h8 hv = *(const h8*)(lah + ((g * BCOL + t) << 3));
            const h8 lv = *(const h8*)(lal + ((g * BCOL + t) << 3));
            const float4 wv0 = *(const float4*)&Wm[g * 8];
            const float4 wv1 = *(const float4*)&Wm[g * 8 + 4];
            const float wv[8] = {wv0.x,wv0.y,wv0.z,wv0.w,wv1.x,wv1.y,wv1.z,wv1.w};
#pragma unroll
            for (int j = 0; j < 8; ++j)
                accm = fmaf(wv[j], (float)hv[j] + (float)lv[j] * LO_INV, accm);
        }
        out[NPIX + h * 160 + w0 + t] = leaky(accm + bcl4[h * 257 + 256]);
    }

    // ---- cl4: 256 class rows in 2 passes; argmax in registers ----
    float mv[5]; int mr[5];
    {
        const float* W4 = Wcl4 + (size_t)h * 32896;
        const float* b4 = bcl4 + h * 257;
#pragma unroll
        for (int c = 0; c < 5; ++c) { mv[c] = -3.4e38f; mr[c] = 0; }
#pragma unroll 1
        for (int p = 0; p < 2; ++p) {
            const int rowOff = (p << 7) + trb;
            f32x4 aH[5], aL[5];
            gemmPass(lah, lal, W4 + rowOff * 128, lrow, lg, aH, aL);
            const int r0 = rowOff + (lg << 2);
            const float4 bb = *(const float4*)&b4[r0];
#pragma unroll
            for (int c = 0; c < 5; ++c)
#pragma unroll
                for (int rr = 0; rr < 4; ++rr) {
                    const float a = aH[c][rr] + aL[c][rr] * LO_INV + ((const float*)&bb)[rr];
                    if (a > mv[c]) { mv[c] = a; mr[c] = r0 + rr; }   // rows ascending per lane
                }
        }
    }
    __syncthreads();                     // act (incl. mask) reads complete; lah now dead
    if (t < BCOL) argb[t] = 0ull;        // argb aliases lah
    __syncthreads();
#pragma unroll
    for (int c = 0; c < 5; ++c)
        atomicMax(&argb[(c << 4) + lrow], packKey(mv[c], mr[c]));
    __syncthreads();

    // ---- finalize: ind ----
    if (t < BCOL) {
        const u64 kk = argb[t];
        ind[h * 160 + w0 + t] = 255 - (int)(kk & 0xFFu);
    }
}

__global__ __launch_bounds__(256) void kB(
    const __hip_bfloat16* __restrict__ xr, const int* __restrict__ ind,
    const float* __restrict__ Wcm2, const float* __restrict__ bcm2,
    const float* __restrict__ Wcm3, const float* __restrict__ bcm3,
    float* __restrict__ out)
{
    // Contiguous mapping: wave wid handles n in [wid*10, wid*10+10).
    // Cross-lane phase: multi-value TREE reduction — levels d=1,2,4 halve the
    // accumulator count (4+2+1 shfls), leaving output og per lane; d=8,16,32
    // finish the 64-lane sum; +3 shfls for the final 8-wide dot. 13 shfls vs 48.
    const int wid = (int)((blockIdx.x * blockDim.x + threadIdx.x) >> 6);
    const int lane = threadIdx.x & 63;
    const int og = ((lane & 1) << 2) | (lane & 2) | ((lane >> 2) & 1);

#pragma unroll 1
    for (int k = 0; k < 10; ++k) {
        const int n = wid * 10 + k;
        const int h_o = n % HH, w_o = n / HH;   // xr source & output position (w-major flat)
        const int h_i = n / WW, w_i = n % WW;   // index-gather position (h-major flat)
        const int ig = ind[h_i * WW + w_i];
        const int sc = (ig >> 4) + (h_i << 4);
        const int rw = ig + (h_i << 8);

        const __hip_bfloat16* xp = xr + (size_t)(h_o * WW + w_o) * 256;
        const float* Wp = Wcm2 + (size_t)sc * 2048;

        float acc[8];
#pragma unroll
        for (int o = 0; o < 8; ++o) acc[o] = 0.f;

        const int c0 = lane * 4;
        const ushort4 xv4 = *(const ushort4*)((const unsigned short*)xp + c0);
        float xf[4];
        xf[0] = __uint_as_float((unsigned int)xv4.x << 16);
        xf[1] = __uint_as_float((unsigned int)xv4.y << 16);
        xf[2] = __uint_as_float((unsigned int)xv4.z << 16);
        xf[3] = __uint_as_float((unsigned int)xv4.w << 16);

#pragma unroll
        for (int i = 0; i < 4; ++i) {
            const float4* wrow = (const float4*)&Wp[(c0 + i) * 8];
            const float4 wa = wrow[0];
            const float4 wb_ = wrow[1];
            const float x = xf[i];
            acc[0] += x * wa.x;  acc[1] += x * wa.y;  acc[2] += x * wa.z;  acc[3] += x * wa.w;
            acc[4] += x * wb_.x; acc[5] += x * wb_.y; acc[6] += x * wb_.z; acc[7] += x * wb_.w;
        }

        // level d=1: 8 -> 4 (lane bit0 selects output-half: 4*b0)
        float t4[4];
#pragma unroll
        for (int i = 0; i < 4; ++i) {
            const float send = (lane & 1) ? acc[i] : acc[i + 4];
            const float keep = (lane & 1) ? acc[i + 4] : acc[i];
            t4[i] = keep + __shfl_xor(send, 1, 64);
        }
        // level d=2: 4 -> 2 (adds 2*b1)
        float t2[2];
#pragma unroll
        for (int i = 0; i < 2; ++i) {
            const float send = (lane & 2) ? t4[i] : t4[i + 2];
            const float keep = (lane & 2) ? t4[i + 2] : t4[i];
            t2[i] = keep + __shfl_xor(send, 2, 64);
        }
        // level d=4: 2 -> 1 (adds b2) — lane now holds output og over its 8-lane cluster
        float t1;
        {
            const float send = (lane & 4) ? t2[0] : t2[1];
            const float keep = (lane & 4) ? t2[1] : t2[0];
            t1 = keep + __shfl_xor(send, 4, 64);
        }
        // finish 64-lane sum
        t1 += __shfl_xor(t1, 8, 64);
        t1 += __shfl_xor(t1, 16, 64);
        t1 += __shfl_xor(t1, 32, 64);

        // y[og] = leaky(sum + b2); r = b3 + sum_o y[o]*w3[o] (8-wide tree dot)
        const float y = leaky(t1 + bcm2[(size_t)sc * 8 + og]);
        float rp = y * Wcm3[(size_t)rw * 8 + og];
        rp += __shfl_xor(rp, 1, 64);
        rp += __shfl_xor(rp, 2, 64);
        rp += __shfl_xor(rp, 4, 64);

        if (lane == 0) {
            const float r = bcm3[rw] + rp;
            const float iv = (float)ind[h_o * WW + w_o];
            out[h_o * WW + w_o] = (iv + r) * (1.0f / 256.0f);
        }
    }
}

extern "C" void kernel_launch(void* const* d_in, const int* in_sizes, int n_in,
                              void* d_out, int out_size, void* d_ws, size_t ws_size,
                              hipStream_t stream)
{
    const float* x_in  = (const float*)d_in[0];
    const float* Wcl1  = (const float*)d_in[1];
    const float* bcl1  = (const float*)d_in[2];
    const float* Wcl2  = (const float*)d_in[3];
    const float* bcl2  = (const float*)d_in[4];
    const float* Wcl3  = (const float*)d_in[5];
    const float* bcl3  = (const float*)d_in[6];
    const float* Wcl4  = (const float*)d_in[7];
    const float* bcl4  = (const float*)d_in[8];
    const float* Wreg1 = (const float*)d_in[9];
    const float* breg1 = (const float*)d_in[10];
    const float* Wcm2  = (const float*)d_in[11];
    const float* bcm2  = (const float*)d_in[12];
    const float* Wcm3  = (const float*)d_in[13];
    const float* bcm3  = (const float*)d_in[14];

    float* out = (float*)d_out;

    // workspace: x_r as bf16 [448][160][256], then ind int32 [448*160]
    __hip_bfloat16* xr = (__hip_bfloat16*)d_ws;
    int* ind = (int*)((char*)d_ws + (size_t)NPIX * 256 * sizeof(__hip_bfloat16));

    kA<<<dim3(HH * 2), dim3(512), 0, stream>>>(x_in, Wcl1, bcl1, Wcl2, bcl2, Wcl3, bcl3,
                                               Wcl4, bcl4, Wreg1, breg1, xr, ind, out);
    kB<<<dim3(1792), dim3(256), 0, stream>>>(xr, ind, Wcm2, bcm2, Wcm3, bcm3, out);
}

// Round 18
// 170.866 us; speedup vs baseline: 1.0807x; 1.0121x over previous
//
#include <hip/hip_runtime.h>
#include <hip/hip_bf16.h>

#define HH 448
#define WW 160
#define NPIX (HH*WW)
#define BCOL 80

typedef unsigned long long u64;
typedef _Float16 h8 __attribute__((ext_vector_type(8)));
typedef _Float16 h4 __attribute__((ext_vector_type(4)));
typedef float f32x4 __attribute__((ext_vector_type(4)));

#define MFMA16(A,B,C) __builtin_amdgcn_mfma_f32_16x16x32_f16(A,B,C,0,0,0)
#define LO_SCALE 4096.0f
#define LO_INV   (1.0f/4096.0f)

__device__ __forceinline__ float leaky(float v) { return v >= 0.f ? v : 0.01f * v; }

__device__ __forceinline__ u64 packKey(float m, int r) {
    unsigned u = __float_as_uint(m);
    u = (u & 0x80000000u) ? ~u : (u | 0x80000000u);   // monotone f32 -> u32
    return ((u64)u << 32) | (unsigned)(255 - r);       // ties -> lowest idx
}

// split a fp32 into fp16 hi + scaled fp16 lo:  a ~= hi + lo*2^-12  (|err| <= 2^-24 |a|)
__device__ __forceinline__ _Float16 splitHi(float v) { return (_Float16)v; }
__device__ __forceinline__ _Float16 splitLo(float v, _Float16 hi) {
    return (_Float16)((v - (float)hi) * LO_SCALE);
}

__device__ __forceinline__ void cvtA(const float4& v0, const float4& v1, h8& ah, h8& al) {
    const float v[8] = {v0.x,v0.y,v0.z,v0.w,v1.x,v1.y,v1.z,v1.w};
#pragma unroll
    for (int j = 0; j < 8; ++j) {
        const _Float16 hi = splitHi(v[j]);
        ah[j] = hi;
        al[j] = splitLo(v[j], hi);
    }
}

__device__ __forceinline__ void cvtHi(const float4& v0, const float4& v1, h8& ah) {
    const float v[8] = {v0.x,v0.y,v0.z,v0.w,v1.x,v1.y,v1.z,v1.w};
#pragma unroll
    for (int j = 0; j < 8; ++j) ah[j] = (_Float16)v[j];
}

// Full-precision pass: 1 row-tile x 5 col-tiles, K=128, 3-term fp16-split.
// Rolled s-loop with 2-K-step rotating weight prefetch (round-14/15 verified, no spill).
// Accumulation order identical to the verified round-8..17 kernels (bitwise-same).
__device__ __forceinline__ void gemmPass(const _Float16* lah, const _Float16* lal,
                                         const float* __restrict__ Wp,
                                         int lrow, int lg,
                                         f32x4 aH[5], f32x4 aL[5])
{
    const f32x4 zero = {0.f, 0.f, 0.f, 0.f};
#pragma unroll
    for (int c = 0; c < 5; ++c) { aH[c] = zero; aL[c] = zero; }

    const float* wb = Wp + lrow * 128 + lg * 8;
    float4 ca0 = *(const float4*)(wb);
    float4 ca1 = *(const float4*)(wb + 4);
    float4 cb0 = *(const float4*)(wb + 32);
    float4 cb1 = *(const float4*)(wb + 36);

    const int ub = lrow;                     // B base col within the 80-col block

#pragma unroll 1
    for (int s = 0; s < 4; s += 2) {
        const int sa = (s + 2) & 3, sb = (s + 3) & 3;   // wrap: s=2 re-reads 0/1 (cache-hot)
        float4 na0 = *(const float4*)(wb + sa * 32);
        float4 na1 = *(const float4*)(wb + sa * 32 + 4);
        float4 nb0 = *(const float4*)(wb + sb * 32);
        float4 nb1 = *(const float4*)(wb + sb * 32 + 4);

        h8 Ah, Al;
        cvtA(ca0, ca1, Ah, Al);
        {
            const int gg = (s << 2) + lg;
#pragma unroll
            for (int c = 0; c < 5; ++c) {
                const int u = gg * BCOL + ub + (c << 4);
                const h8 Bh = *(const h8*)(lah + (u << 3));
                const h8 Bl = *(const h8*)(lal + (u << 3));
                aH[c] = MFMA16(Ah, Bh, aH[c]);
                aL[c] = MFMA16(Ah, Bl, aL[c]);
                aL[c] = MFMA16(Al, Bh, aL[c]);
            }
        }
        cvtA(cb0, cb1, Ah, Al);
        {
            const int gg = ((s + 1) << 2) + lg;
#pragma unroll
            for (int c = 0; c < 5; ++c) {
                const int u = gg * BCOL + ub + (c << 4);
                const h8 Bh = *(const h8*)(lah + (u << 3));
                const h8 Bl = *(const h8*)(lal + (u << 3));
                aH[c] = MFMA16(Ah, Bh, aH[c]);
                aL[c] = MFMA16(Ah, Bl, aL[c]);
                aL[c] = MFMA16(Al, Bh, aL[c]);
            }
        }
        ca0 = na0; ca1 = na1; cb0 = nb0; cb1 = nb1;
    }
}

// Hi-only pass for reg1: xr is bf16-quantized and /256-attenuated downstream, so
// fp16-hi precision (rel err ~1e-3, same order as bf16 storage) suffices.
// 20 MFMA + 20 B-reads per pass (vs 60/40); ind & mask paths untouched.
__device__ __forceinline__ void gemmPassHi(const _Float16* lah,
                                           const float* __restrict__ Wp,
                                           int lrow, int lg,
                                           f32x4 aH[5])
{
    const f32x4 zero = {0.f, 0.f, 0.f, 0.f};
#pragma unroll
    for (int c = 0; c < 5; ++c) aH[c] = zero;

    const float* wb = Wp + lrow * 128 + lg * 8;
    float4 ca0 = *(const float4*)(wb);
    float4 ca1 = *(const float4*)(wb + 4);
    float4 cb0 = *(const float4*)(wb + 32);
    float4 cb1 = *(const float4*)(wb + 36);

    const int ub = lrow;

#pragma unroll 1
    for (int s = 0; s < 4; s += 2) {
        const int sa = (s + 2) & 3, sb = (s + 3) & 3;
        float4 na0 = *(const float4*)(wb + sa * 32);
        float4 na1 = *(const float4*)(wb + sa * 32 + 4);
        float4 nb0 = *(const float4*)(wb + sb * 32);
        float4 nb1 = *(const float4*)(wb + sb * 32 + 4);

        h8 Ah;
        cvtHi(ca0, ca1, Ah);
        {
            const int gg = (s << 2) + lg;
#pragma unroll
            for (int c = 0; c < 5; ++c) {
                const int u = gg * BCOL + ub + (c << 4);
                const h8 Bh = *(const h8*)(lah + (u << 3));
                aH[c] = MFMA16(Ah, Bh, aH[c]);
            }
        }
        cvtHi(cb0, cb1, Ah);
        {
            const int gg = ((s + 1) << 2) + lg;
#pragma unroll
            for (int c = 0; c < 5; ++c) {
                const int u = gg * BCOL + ub + (c << 4);
                const h8 Bh = *(const h8*)(lah + (u << 3));
                aH[c] = MFMA16(Ah, Bh, aH[c]);
            }
        }
        ca0 = na0; ca1 = na1; cb0 = nb0; cb1 = nb1;
    }
}

__global__ __launch_bounds__(512, 4) void kA(
    const float* __restrict__ x_in,
    const float* __restrict__ Wcl1, const float* __restrict__ bcl1,
    const float* __restrict__ Wcl2, const float* __restrict__ bcl2,
    const float* __restrict__ Wcl3, const float* __restrict__ bcl3,
    const float* __restrict__ Wcl4, const float* __restrict__ bcl4,
    const float* __restrict__ Wreg1, const float* __restrict__ breg1,
    __hip_bfloat16* __restrict__ xr, int* __restrict__ ind, float* __restrict__ out)
{
    // 8-wave block, 80 cols of one h. LDS exactly 40960 B -> 2 blocks/CU (16 waves).
    __shared__ alignas(16) _Float16 lah[16 * BCOL * 8];   // 20480 B: act hi, K-packed
    __shared__ alignas(16) _Float16 lal[16 * BCOL * 8];   // 20480 B: act lo*4096
    u64* argb = reinterpret_cast<u64*>(lah);  // aliased AFTER act is dead (post-cl4)

    // XCD pairing: both 80-col halves of one h land on the same XCD (bid%8)
    const int bid = blockIdx.x;
    const int r16 = bid & 15;
    const int h = ((bid >> 4) << 3) | (r16 & 7);
    const int w0 = ((r16 >> 3) & 1) * BCOL;

    const int t = threadIdx.x;
    const int wvid = t >> 6;                 // 0..7
    const int l = t & 63;
    const int lrow = l & 15, lg = l >> 4;
    const int trb = wvid * 16;               // wave's row base within a 128-row pass

    // ---- stage x: fp32 -> fp16-split pairs, K-packed [g][col][8] ----
#pragma unroll 1
    for (int k = 0; k < 3; ++k) {
        const int id = t + (k << 9);         // 0..1279 = (g, col)
        if (id < 16 * BCOL) {
            const int g = id / BCOL, col = id - g * BCOL;
            float v[8];
#pragma unroll
            for (int j = 0; j < 8; ++j)
                v[j] = x_in[(size_t)(g * 8 + j) * 71680 + h * 160 + w0 + col];
            h8 hh, ll;
#pragma unroll
            for (int j = 0; j < 8; ++j) {
                const _Float16 hi = splitHi(v[j]);
                hh[j] = hi;
                ll[j] = splitLo(v[j], hi);
            }
            const int u = g * BCOL + col;
            *(h8*)(lah + (u << 3)) = hh;
            *(h8*)(lal + (u << 3)) = ll;
        }
    }
    __syncthreads();

    // ---- reg1: 256 rows in 2 hi-only passes, bf16 out to xr (no LDS writes) ----
    {
        const float* W1 = Wreg1 + (size_t)h * 32768;
        const float* b1 = breg1 + h * 256;
#pragma unroll 1
        for (int p = 0; p < 2; ++p) {
            const int rowOff = (p << 7) + trb;
            f32x4 aH[5];
            gemmPassHi(lah, W1 + rowOff * 128, lrow, lg, aH);
            const int r0 = rowOff + (lg << 2);
            const float4 bb = *(const float4*)&b1[r0];
#pragma unroll
            for (int c = 0; c < 5; ++c) {
                const int col = w0 + (c << 4) + lrow;
                alignas(8) unsigned short us[4];
#pragma unroll
                for (int r = 0; r < 4; ++r) {
                    const float a = aH[c][r] + ((const float*)&bb)[r];
                    __hip_bfloat16 bv = __float2bfloat16(leaky(a));
                    us[r] = *(const unsigned short*)&bv;
                }
                *(uint2*)(xr + (((size_t)(h * 160 + col)) << 8) + r0) = *(const uint2*)us;
            }
        }
    }

    // ---- cl1..cl3: in-place act update (compute -> barrier -> write -> barrier) ----
#pragma unroll 1
    for (int L = 0; L < 3; ++L) {
        const float* W = (L == 0) ? Wcl1 + (size_t)h * 16384
                       : (L == 1) ? Wcl2 + (size_t)h * 16384
                                  : Wcl3 + (size_t)h * 16384;
        const float* b = (L == 0) ? bcl1 + (h << 7)
                       : (L == 1) ? bcl2 + (h << 7)
                                  : bcl3 + (h << 7);
        f32x4 aH[5], aL[5];
        gemmPass(lah, lal, W + trb * 128, lrow, lg, aH, aL);
        const int r0 = trb + (lg << 2);
        const float4 bb = *(const float4*)&b[r0];
        float nv[5][4];
#pragma unroll
        for (int c = 0; c < 5; ++c)
#pragma unroll
            for (int rr = 0; rr < 4; ++rr)
                nv[c][rr] = leaky(aH[c][rr] + aL[c][rr] * LO_INV + ((const float*)&bb)[rr]);
        __syncthreads();                 // all reads of old act done
        {
            const int g = r0 >> 3, off = r0 & 7;
#pragma unroll
            for (int c = 0; c < 5; ++c) {
                const int col = (c << 4) + lrow;
                h4 wh, wl;
#pragma unroll
                for (int rr = 0; rr < 4; ++rr) {
                    const _Float16 hi = splitHi(nv[c][rr]);
                    wh[rr] = hi;
                    wl[rr] = splitLo(nv[c][rr], hi);
                }
                *(h4*)(lah + ((g * BCOL + col) << 3) + off) = wh;
                *(h4*)(lal + ((g * BCOL + col) << 3) + off) = wl;
            }
        }
        __syncthreads();
    }

    // ---- mask row (pre-cl4; act holds cl3 output — identical values) ----
    if (t < BCOL) {
        const float* Wm = Wcl4 + (size_t)h * 32896 + 32768;   // class row 256
        float accm = 0.f;
#pragma unroll 2
        for (int g = 0; g < 16; ++g) {
            const h8 hv = *(const h8*)(lah + ((g * BCOL + t) << 3));
            const h8 lv = *(const h8*)(lal + ((g * BCOL + t) << 3));
            const float4 wv0 = *(const float4*)&Wm[g * 8];
            const float4 wv1 = *(const float4*)&Wm[g * 8 + 4];
            const float wv[8] = {wv0.x,wv0.y,wv0.z,wv0.w,wv1.x,wv1.y,wv1.z,wv1.w};
#pragma unroll
            for (int j = 0; j < 8; ++j)
                accm = fmaf(wv[j], (float)hv[j] + (float)lv[j] * LO_INV, accm);
        }
        out[NPIX + h * 160 + w0 + t] = leaky(accm + bcl4[h * 257 + 256]);
    }

    // ---- cl4: 256 class rows in 2 passes; argmax in registers (full precision) ----
    float mv[5]; int mr[5];
    {
        const float* W4 = Wcl4 + (size_t)h * 32896;
        const float* b4 = bcl4 + h * 257;
#pragma unroll
        for (int c = 0; c < 5; ++c) { mv[c] = -3.4e38f; mr[c] = 0; }
#pragma unroll 1
        for (int p = 0; p < 2; ++p) {
            const int rowOff = (p << 7) + trb;
            f32x4 aH[5], aL[5];
            gemmPass(lah, lal, W4 + rowOff * 128, lrow, lg, aH, aL);
            const int r0 = rowOff + (lg << 2);
            const float4 bb = *(const float4*)&b4[r0];
#pragma unroll
            for (int c = 0; c < 5; ++c)
#pragma unroll
                for (int rr = 0; rr < 4; ++rr) {
                    const float a = aH[c][rr] + aL[c][rr] * LO_INV + ((const float*)&bb)[rr];
                    if (a > mv[c]) { mv[c] = a; mr[c] = r0 + rr; }   // rows ascending per lane
                }
        }
    }
    __syncthreads();                     // act (incl. mask) reads complete; lah now dead
    if (t < BCOL) argb[t] = 0ull;        // argb aliases lah
    __syncthreads();
#pragma unroll
    for (int c = 0; c < 5; ++c)
        atomicMax(&argb[(c << 4) + lrow], packKey(mv[c], mr[c]));
    __syncthreads();

    // ---- finalize: ind ----
    if (t < BCOL) {
        const u64 kk = argb[t];
        ind[h * 160 + w0 + t] = 255 - (int)(kk & 0xFFu);
    }
}

__global__ __launch_bounds__(256) void kB(
    const __hip_bfloat16* __restrict__ xr, const int* __restrict__ ind,
    const float* __restrict__ Wcm2, const float* __restrict__ bcm2,
    const float* __restrict__ Wcm3, const float* __restrict__ bcm3,
    float* __restrict__ out)
{
    // Contiguous mapping: wave wid handles n in [wid*10, wid*10+10).
    // Multi-value tree reduction: 13 cross-lane ops per n (round-17 verified).
    const int wid = (int)((blockIdx.x * blockDim.x + threadIdx.x) >> 6);
    const int lane = threadIdx.x & 63;
    const int og = ((lane & 1) << 2) | (lane & 2) | ((lane >> 2) & 1);

#pragma unroll 1
    for (int k = 0; k < 10; ++k) {
        const int n = wid * 10 + k;
        const int h_o = n % HH, w_o = n / HH;   // xr source & output position (w-major flat)
        const int h_i = n / WW, w_i = n % WW;   // index-gather position (h-major flat)
        const int ig = ind[h_i * WW + w_i];
        const int sc = (ig >> 4) + (h_i << 4);
        const int rw = ig + (h_i << 8);

        const __hip_bfloat16* xp = xr + (size_t)(h_o * WW + w_o) * 256;
        const float* Wp = Wcm2 + (size_t)sc * 2048;

        float acc[8];
#pragma unroll
        for (int o = 0; o < 8; ++o) acc[o] = 0.f;

        const int c0 = lane * 4;
        const ushort4 xv4 = *(const ushort4*)((const unsigned short*)xp + c0);
        float xf[4];
        xf[0] = __uint_as_float((unsigned int)xv4.x << 16);
        xf[1] = __uint_as_float((unsigned int)xv4.y << 16);
        xf[2] = __uint_as_float((unsigned int)xv4.z << 16);
        xf[3] = __uint_as_float((unsigned int)xv4.w << 16);

#pragma unroll
        for (int i = 0; i < 4; ++i) {
            const float4* wrow = (const float4*)&Wp[(c0 + i) * 8];
            const float4 wa = wrow[0];
            const float4 wb_ = wrow[1];
            const float x = xf[i];
            acc[0] += x * wa.x;  acc[1] += x * wa.y;  acc[2] += x * wa.z;  acc[3] += x * wa.w;
            acc[4] += x * wb_.x; acc[5] += x * wb_.y; acc[6] += x * wb_.z; acc[7] += x * wb_.w;
        }

        // level d=1: 8 -> 4 (lane bit0 selects output-half: 4*b0)
        float t4[4];
#pragma unroll
        for (int i = 0; i < 4; ++i) {
            const float send = (lane & 1) ? acc[i] : acc[i + 4];
            const float keep = (lane & 1) ? acc[i + 4] : acc[i];
            t4[i] = keep + __shfl_xor(send, 1, 64);
        }
        // level d=2: 4 -> 2 (adds 2*b1)
        float t2[2];
#pragma unroll
        for (int i = 0; i < 2; ++i) {
            const float send = (lane & 2) ? t4[i] : t4[i + 2];
            const float keep = (lane & 2) ? t4[i + 2] : t4[i];
            t2[i] = keep + __shfl_xor(send, 2, 64);
        }
        // level d=4: 2 -> 1 (adds b2) — lane now holds output og over its 8-lane cluster
        float t1;
        {
            const float send = (lane & 4) ? t2[0] : t2[1];
            const float keep = (lane & 4) ? t2[1] : t2[0];
            t1 = keep + __shfl_xor(send, 4, 64);
        }
        // finish 64-lane sum
        t1 += __shfl_xor(t1, 8, 64);
        t1 += __shfl_xor(t1, 16, 64);
        t1 += __shfl_xor(t1, 32, 64);

        // y[og] = leaky(sum + b2); r = b3 + sum_o y[o]*w3[o] (8-wide tree dot)
        const float y = leaky(t1 + bcm2[(size_t)sc * 8 + og]);
        float rp = y * Wcm3[(size_t)rw * 8 + og];
        rp += __shfl_xor(rp, 1, 64);
        rp += __shfl_xor(rp, 2, 64);
        rp += __shfl_xor(rp, 4, 64);

        if (lane == 0) {
            const float r = bcm3[rw] + rp;
            const float iv = (float)ind[h_o * WW + w_o];
            out[h_o * WW + w_o] = (iv + r) * (1.0f / 256.0f);
        }
    }
}

extern "C" void kernel_launch(void* const* d_in, const int* in_sizes, int n_in,
                              void* d_out, int out_size, void* d_ws, size_t ws_size,
                              hipStream_t stream)
{
    const float* x_in  = (const float*)d_in[0];
    const float* Wcl1  = (const float*)d_in[1];
    const float* bcl1  = (const float*)d_in[2];
    const float* Wcl2  = (const float*)d_in[3];
    const float* bcl2  = (const float*)d_in[4];
    const float* Wcl3  = (const float*)d_in[5];
    const float* bcl3  = (const float*)d_in[6];
    const float* Wcl4  = (const float*)d_in[7];
    const float* bcl4  = (const float*)d_in[8];
    const float* Wreg1 = (const float*)d_in[9];
    const float* breg1 = (const float*)d_in[10];
    const float* Wcm2  = (const float*)d_in[11];
    const float* bcm2  = (const float*)d_in[12];
    const float* Wcm3  = (const float*)d_in[13];
    const float* bcm3  = (const float*)d_in[14];

    float* out = (float*)d_out;

    // workspace: x_r as bf16 [448][160][256], then ind int32 [448*160]
    __hip_bfloat16* xr = (__hip_bfloat16*)d_ws;
    int* ind = (int*)((char*)d_ws + (size_t)NPIX * 256 * sizeof(__hip_bfloat16));

    kA<<<dim3(HH * 2), dim3(512), 0, stream>>>(x_in, Wcl1, bcl1, Wcl2, bcl2, Wcl3, bcl3,
                                               Wcl4, bcl4, Wreg1, breg1, xr, ind, out);
    kB<<<dim3(1792), dim3(256), 0, stream>>>(xr, ind, Wcm2, bcm2, Wcm3, bcm3, out);
}